// Round 2
// baseline (256.695 us; speedup 1.0000x reference)
//
#include <hip/hip_runtime.h>

// incidence_matrix_learn on MI355X — round 10.
// Round-9 post-mortem: counted-vmcnt ring (distance 3) was NULL (91.9->89.9us).
// Combined with round-7-vs-8 (2x TLP also null) and the register wall
// (32-row full-K A = ~210 regs/wave -> hard 2 waves/SIMD; 16-row waves double
// LDS-bytes/MFMA to a floor below current perf), neither pipelining nor
// occupancy can move this structure. All pipes idle (Mfma 16/VALU 15/LDS 21%/
// L2 20%/HBM 9%) -> unidentified per-chunk stall. Robust move: halve the WORK.
// sim is symmetric: compute only tile pairs (tu <= tv), harvest row-sums for
// u-rows AND col-sums for v-rows from each 64x64 tile -> 55.8% of the FLOPs
// and B-traffic. Partial se/pos go to a non-atomic workspace sp[slot][gid]
// (row-side writes slot tv, col-side slot tu: disjoint, every slot written
// exactly once), summed by a new loss_reduce kernel.
// Validated algebra (rounds 1-9, absmax 0.0): top-k no-op; P via labels;
// fixed-shift-10 LSE; bf16 nhat; cnt = label-histogram - 1; counted-vmcnt
// ring staging (round 9, verified correct).

#define DDIM 512
#define BATCH 64
#define NGID 65536   // 64*640 + 64*384 node-row slots across both scales

typedef __attribute__((ext_vector_type(8))) short short8;
typedef __attribute__((ext_vector_type(4))) float f32x4;

__device__ __forceinline__ unsigned short f2bf(float f) {
  unsigned int u = __float_as_uint(f);
  u += 0x7fffu + ((u >> 16) & 1u);   // RNE
  return (unsigned short)(u >> 16);
}

__device__ __forceinline__ void async16(const void* g, void* l) {
  __builtin_amdgcn_global_load_lds(
      (const __attribute__((address_space(1))) unsigned int*)g,
      (__attribute__((address_space(3))) unsigned int*)l, 16, 0, 0);
}

// Fused prep kernel, 256 threads. Blocks [0,1024): adj (both scales) + acc
// init. Blocks [1024, 1024+16384): normalize, one WAVE per node row.
__global__ __launch_bounds__(256) void prep_kernel(
    const float* __restrict__ enod0, const float* __restrict__ ehy0,
    const float* __restrict__ enod1, const float* __restrict__ ehy1,
    float* __restrict__ adj0, float* __restrict__ adj1,
    int* __restrict__ labels0, int* __restrict__ labels1,
    const float* __restrict__ x0, const float* __restrict__ w0,
    const float* __restrict__ x1, const float* __restrict__ w1,
    unsigned short* __restrict__ nhat0, unsigned short* __restrict__ nhat1,
    float* __restrict__ acc) {
  const int t = threadIdx.x;
  if (blockIdx.x < 1024) {
    // ---- adj path ----
    if (blockIdx.x == 0 && t == 0) { acc[0] = 0.f; acc[1] = 0.f; }
    const bool s0 = blockIdx.x < 640;
    const int n = s0 ? blockIdx.x : blockIdx.x - 640;
    const int H = s0 ? 128 : 64;
    const float* enod = s0 ? enod0 : enod1;
    const float* ehy = s0 ? ehy0 : ehy1;
    float* out_adj = s0 ? adj0 : adj1;
    int* labels = s0 ? labels0 : labels1;
    __shared__ float erow[DDIM];
    __shared__ float red[128];
    __shared__ int lab;
    if (t < 128) ((float4*)erow)[t] = ((const float4*)(enod + (size_t)n * DDIM))[t];
    if (t == 0) lab = -1;
    __syncthreads();
    float v = 0.f;
    if (t < H) {
      const float4* hr = (const float4*)(ehy + (size_t)t * DDIM);
      float a = 0.f;
      #pragma unroll 8
      for (int d = 0; d < DDIM / 4; ++d) {
        float4 h = hr[d];
        float4 e = ((const float4*)erow)[d];
        a = fmaf(h.x, e.x, a); a = fmaf(h.y, e.y, a);
        a = fmaf(h.z, e.z, a); a = fmaf(h.w, e.w, a);
      }
      v = fmaxf(0.f, 3.0f * a);
    }
    if (t < 128) red[t] = v;
    __syncthreads();
    for (int s = 64; s > 0; s >>= 1) {
      if (t < s) red[t] = fmaxf(red[t], red[t + s]);
      __syncthreads();
    }
    const float mx = red[0];
    __syncthreads();
    const float e = (t < H) ? __expf(v - mx) : 0.f;
    if (t < 128) red[t] = e;
    __syncthreads();
    for (int s = 64; s > 0; s >>= 1) {
      if (t < s) red[t] += red[t + s];
      __syncthreads();
    }
    const float sum = red[0];
    if (t < H) {
      const float adj = e / sum;
      const float bin = (adj > 0.5f) ? 1.0f : 0.0f;
      out_adj[(size_t)n * H + t] = bin;
      if (bin > 0.f) lab = t;
    }
    __syncthreads();
    if (t == 0) labels[n] = lab;
  } else {
    // ---- normalize path: wave per row ----
    const int wave = t >> 6;
    const int lane = t & 63;
    const int g = (blockIdx.x - 1024) * 4 + wave;   // global row id, < 65536
    const bool s0 = g < BATCH * 640;
    const int gg = s0 ? g : g - BATCH * 640;
    const int N = s0 ? 640 : 384;
    const int L = s0 ? 512 : 256;
    const float* x = s0 ? x0 : x1;
    const float* w = s0 ? w0 : w1;
    unsigned short* nhat = s0 ? nhat0 : nhat1;
    const int b = gg / N;
    const int n = gg - b * N;
    const float* src = (n < L) ? (x + ((size_t)b * L + n) * DDIM)
                               : (w + (size_t)(n - L) * DDIM);
    const float4* rowp = (const float4*)src;
    const float4 v0 = rowp[lane];
    const float4 v1 = rowp[lane + 64];
    float ss = v0.x * v0.x + v0.y * v0.y + v0.z * v0.z + v0.w * v0.w +
               v1.x * v1.x + v1.y * v1.y + v1.z * v1.z + v1.w * v1.w;
    #pragma unroll
    for (int off = 32; off > 0; off >>= 1) ss += __shfl_xor(ss, off);
    const float rinv = 1.0f / fmaxf(sqrtf(ss), 1e-12f);
    ushort4 o0, o1;
    o0.x = f2bf(v0.x * rinv); o0.y = f2bf(v0.y * rinv);
    o0.z = f2bf(v0.z * rinv); o0.w = f2bf(v0.w * rinv);
    o1.x = f2bf(v1.x * rinv); o1.y = f2bf(v1.y * rinv);
    o1.z = f2bf(v1.z * rinv); o1.w = f2bf(v1.w * rinv);
    ushort4* op = (ushort4*)(nhat + ((size_t)b * N + n) * DDIM);
    op[lane] = o0;
    op[lane + 64] = o1;
  }
}

// 2 blocks. cnt[i] = hist[lab[i]] - 1 via 128-bin LDS label histogram.
__global__ __launch_bounds__(256) void cnt_kernel(
    const int* __restrict__ labels0, int* __restrict__ cnt0,
    const int* __restrict__ labels1, int* __restrict__ cnt1,
    int* __restrict__ valid) {
  const bool s0 = blockIdx.x == 0;
  const int* labels = s0 ? labels0 : labels1;
  int* cnt = s0 ? cnt0 : cnt1;
  int* validcnt = s0 ? valid : valid + 1;
  const int N = s0 ? 640 : 384;
  __shared__ int lab[640];
  __shared__ int hist[128];
  __shared__ int vc;
  const int t = threadIdx.x;
  if (t == 0) vc = 0;
  if (t < 128) hist[t] = 0;
  for (int i = t; i < N; i += 256) lab[i] = labels[i];
  __syncthreads();
  for (int i = t; i < N; i += 256)
    if (lab[i] >= 0) atomicAdd(&hist[lab[i]], 1);
  __syncthreads();
  int lv = 0;
  for (int i = t; i < N; i += 256) {
    const int c = (lab[i] >= 0) ? hist[lab[i]] - 1 : 0;
    cnt[i] = c;
    if (c > 0) ++lv;
  }
  if (lv > 0) atomicAdd(&vc, lv);
  __syncthreads();
  if (t == 0) *validcnt = vc;
}

// Symmetric MFMA lse kernel, 128 threads (2 waves) per (b, tu<=tv) tile pair.
// Block computes the 64x64 tile sim(u in tu, v in tv), K=512 in 8 chunks of
// 64k staged through a compile-time ring-3 LDS (counted vmcnt, round-9
// verified skeleton). Row-sums (se/pos over v) -> sp[tv][gid(u)];
// col-sums (over u) -> sp[tu][gid(v)] (off-diag only). Each (slot,gid) has
// exactly one writer; slots 0..nt-1 per gid are all written exactly once.
__global__ __launch_bounds__(128, 2) void lse_kernel(
    const unsigned short* __restrict__ nhat0, const int* __restrict__ labels0,
    const unsigned short* __restrict__ nhat1, const int* __restrict__ labels1,
    float2* __restrict__ sp) {
  __shared__ short8 Bbuf[3][512];   // ring-3 x 8 KB, frag-order
  __shared__ float2 redC[2][64];    // cross-wave col-sum combine
  const int tid = threadIdx.x;
  const bool s0 = blockIdx.x < 3520;         // 55 pairs * 64 batches
  const int i = s0 ? blockIdx.x : blockIdx.x - 3520;
  const int b = i & 63;        // XCD swizzle: batch fixes XCD residue
  int p = i >> 6;              // pair index within scale
  const int nt = s0 ? 10 : 6;
  int tu = 0;
  while (p >= nt - tu) { p -= nt - tu; ++tu; }   // triangular decode
  const int tv = tu + p;
  const bool diag = (tu == tv);
  const int N = s0 ? 640 : 384;
  const unsigned short* nhat = s0 ? nhat0 : nhat1;
  const int* labels = s0 ? labels0 : labels1;
  const int gbase = s0 ? b * 640 : 40960 + b * 384;

  const int wave = tid >> 6;   // 0..1
  const int lane = tid & 63;
  const int lrow = lane & 15;   // A-row within 16 / B-col / C-col
  const int lq = lane >> 4;     // k-chunk selector / C row group

  const size_t base = (size_t)b * N * DDIM;
  const int rw0 = tu * 64 + wave * 32;   // wave owns u-rows rw0 .. rw0+31
  const unsigned short* Ap0 = nhat + base + (size_t)(rw0 + lrow) * DDIM + lq * 8;
  const unsigned short* Ap1 = Ap0 + (size_t)16 * DDIM;
  short8 a0[16], a1[16];
  #pragma unroll
  for (int ks = 0; ks < 16; ++ks) {
    a0[ks] = *(const short8*)(Ap0 + ks * 32);
    a1[ks] = *(const short8*)(Ap1 + ks * 32);
  }
  int labn[2][4];
  #pragma unroll
  for (int s = 0; s < 2; ++s)
    #pragma unroll
    for (int r = 0; r < 4; ++r) labn[s][r] = labels[rw0 + s * 16 + lq * 4 + r];
  int labm[4];
  #pragma unroll
  for (int j = 0; j < 4; ++j) labm[j] = labels[tv * 64 + j * 16 + lrow];

  __syncthreads();   // full vmcnt drain: ring counting starts clean

  const unsigned short* Bp = nhat + base + (size_t)(tv * 64) * DDIM;
  const int f0 = wave * 4;
  // prologue: chunks 0,1 -> slots 0,1 (4 frags per wave per chunk)
  #pragma unroll
  for (int pc = 0; pc < 2; ++pc) {
    #pragma unroll
    for (int fi = 0; fi < 4; ++fi) {
      const int f = f0 + fi, j = f >> 1, ks = f & 1;
      async16(Bp + (size_t)(j * 16 + lrow) * DDIM + pc * 64 + ks * 32 + lq * 8,
              &Bbuf[pc][f * 64]);
    }
  }

  f32x4 acc[4][2];
  #pragma unroll
  for (int j = 0; j < 4; ++j) {
    acc[j][0] = (f32x4){0.f, 0.f, 0.f, 0.f};
    acc[j][1] = (f32x4){0.f, 0.f, 0.f, 0.f};
  }
  #pragma unroll
  for (int kc = 0; kc < 8; ++kc) {
    // own 4 loads of chunk kc done; next chunk's 4 stay in flight
    if (kc < 7) asm volatile("s_waitcnt vmcnt(4)" ::: "memory");
    else        asm volatile("s_waitcnt vmcnt(0)" ::: "memory");
    __builtin_amdgcn_s_barrier();   // both waves' chunk-kc loads landed;
                                    // readers of chunk kc-1 all done
    if (kc < 6) {
      short8* dst = &Bbuf[(kc + 2) % 3][0];   // slot of chunk kc-1 (safe)
      #pragma unroll
      for (int fi = 0; fi < 4; ++fi) {
        const int f = f0 + fi, j = f >> 1, ks = f & 1;
        async16(Bp + (size_t)(j * 16 + lrow) * DDIM + (kc + 2) * 64 + ks * 32 + lq * 8,
                dst + f * 64);
      }
    }
    const short8* bb = &Bbuf[kc % 3][0];
    #pragma unroll
    for (int ks = 0; ks < 2; ++ks) {
      const short8 b0 = bb[(0 + ks) * 64 + lane];
      const short8 b1 = bb[(2 + ks) * 64 + lane];
      const short8 b2 = bb[(4 + ks) * 64 + lane];
      const short8 b3 = bb[(6 + ks) * 64 + lane];
      const short8 av0 = a0[kc * 2 + ks];
      const short8 av1 = a1[kc * 2 + ks];
      acc[0][0] = __builtin_amdgcn_mfma_f32_16x16x32_bf16(av0, b0, acc[0][0], 0, 0, 0);
      acc[0][1] = __builtin_amdgcn_mfma_f32_16x16x32_bf16(av1, b0, acc[0][1], 0, 0, 0);
      acc[1][0] = __builtin_amdgcn_mfma_f32_16x16x32_bf16(av0, b1, acc[1][0], 0, 0, 0);
      acc[1][1] = __builtin_amdgcn_mfma_f32_16x16x32_bf16(av1, b1, acc[1][1], 0, 0, 0);
      acc[2][0] = __builtin_amdgcn_mfma_f32_16x16x32_bf16(av0, b2, acc[2][0], 0, 0, 0);
      acc[2][1] = __builtin_amdgcn_mfma_f32_16x16x32_bf16(av1, b2, acc[2][1], 0, 0, 0);
      acc[3][0] = __builtin_amdgcn_mfma_f32_16x16x32_bf16(av0, b3, acc[3][0], 0, 0, 0);
      acc[3][1] = __builtin_amdgcn_mfma_f32_16x16x32_bf16(av1, b3, acc[3][1], 0, 0, 0);
    }
  }

  // epilogue: row-side (u) and col-side (v) partial sums from one tile
  float rSE[2][4] = {{0.f, 0.f, 0.f, 0.f}, {0.f, 0.f, 0.f, 0.f}};
  float rPOS[2][4] = {{0.f, 0.f, 0.f, 0.f}, {0.f, 0.f, 0.f, 0.f}};
  float cSE[4] = {0.f, 0.f, 0.f, 0.f};
  float cPOS[4] = {0.f, 0.f, 0.f, 0.f};
  #pragma unroll
  for (int j = 0; j < 4; ++j) {
    const int v = tv * 64 + j * 16 + lrow;
    #pragma unroll
    for (int s = 0; s < 2; ++s) {
      const int u0 = rw0 + s * 16 + lq * 4;
      #pragma unroll
      for (int r = 0; r < 4; ++r) {
        const float sim = acc[j][s][r] * 10.0f;    // 1/TAU
        const float e = __expf(sim - 10.0f);       // fixed shift (diag max)
        rSE[s][r] += e;
        const bool match = (labn[s][r] >= 0) && (labm[j] == labn[s][r]);
        if (match && v != u0 + r) rPOS[s][r] += sim;
        if (!diag) {
          cSE[j] += e;
          if (match) cPOS[j] += sim;   // u != v automatic off-diag
        }
      }
    }
  }

  // row reduce across the 16 col-lanes, then direct store to sp[tv][gid(u)]
  #pragma unroll
  for (int off = 1; off <= 8; off <<= 1) {
    #pragma unroll
    for (int s = 0; s < 2; ++s)
      #pragma unroll
      for (int r = 0; r < 4; ++r) {
        rSE[s][r] += __shfl_xor(rSE[s][r], off);
        rPOS[s][r] += __shfl_xor(rPOS[s][r], off);
      }
  }
  if (lrow == 0) {
    #pragma unroll
    for (int s = 0; s < 2; ++s)
      #pragma unroll
      for (int r = 0; r < 4; ++r) {
        const int u = rw0 + s * 16 + lq * 4 + r;
        float2 st; st.x = rSE[s][r]; st.y = rPOS[s][r];
        sp[(size_t)tv * NGID + gbase + u] = st;
      }
  }

  // col reduce across lq groups (lanes ^16, ^32), combine waves via LDS,
  // store to sp[tu][gid(v)] (off-diag only)
  if (!diag) {
    #pragma unroll
    for (int off = 16; off <= 32; off <<= 1) {
      #pragma unroll
      for (int j = 0; j < 4; ++j) {
        cSE[j] += __shfl_xor(cSE[j], off);
        cPOS[j] += __shfl_xor(cPOS[j], off);
      }
    }
    if (lane < 16) {
      #pragma unroll
      for (int j = 0; j < 4; ++j) {
        float2 st; st.x = cSE[j]; st.y = cPOS[j];
        redC[wave][j * 16 + lane] = st;
      }
    }
    __syncthreads();
    if (tid < 64) {
      const float2 c0 = redC[0][tid];
      const float2 c1 = redC[1][tid];
      const int v = tv * 64 + tid;
      float2 st; st.x = c0.x + c1.x; st.y = c0.y + c1.y;
      sp[(size_t)tu * NGID + gbase + v] = st;
    }
  }
}

// Sum per-gid partials over the nt tile slots, apply LSE + pos/cnt, reduce.
__global__ __launch_bounds__(256) void loss_reduce(
    const float2* __restrict__ sp, const int* __restrict__ cnt0,
    const int* __restrict__ cnt1, float* __restrict__ acc) {
  __shared__ float r0[4], r1[4];
  const int t = threadIdx.x;
  float l0 = 0.f, l1 = 0.f;
  for (int g = blockIdx.x * 256 + t; g < NGID; g += 64 * 256) {
    const bool is0 = g < 40960;
    const int nslots = is0 ? 10 : 6;
    float se = 0.f, pos = 0.f;
    for (int s = 0; s < nslots; ++s) {
      const float2 v = sp[(size_t)s * NGID + g];
      se += v.x; pos += v.y;
    }
    const int n = is0 ? (g % 640) : ((g - 40960) % 384);
    const int c = is0 ? cnt0[n] : cnt1[n];
    if (c > 0) {
      const float v = (10.0f + logf(se)) - pos / (float)c;
      if (is0) l0 += v; else l1 += v;
    }
  }
  #pragma unroll
  for (int off = 32; off > 0; off >>= 1) {
    l0 += __shfl_xor(l0, off);
    l1 += __shfl_xor(l1, off);
  }
  if ((t & 63) == 0) { r0[t >> 6] = l0; r1[t >> 6] = l1; }
  __syncthreads();
  if (t == 0) {
    atomicAdd(&acc[0], r0[0] + r0[1] + r0[2] + r0[3]);
    atomicAdd(&acc[1], r1[0] + r1[1] + r1[2] + r1[3]);
  }
}

__global__ void final_kernel(const float* __restrict__ acc,
                             const int* __restrict__ valid,
                             float* __restrict__ out) {
  float l = 0.f;
  if (valid[0] > 0) l += acc[0] / (float)(BATCH * valid[0]);
  if (valid[1] > 0) l += acc[1] / (float)(BATCH * valid[1]);
  out[0] = l;
}

extern "C" void kernel_launch(void* const* d_in, const int* in_sizes, int n_in,
                              void* d_out, int out_size, void* d_ws,
                              size_t ws_size, hipStream_t stream) {
  const float* x0 = (const float*)d_in[0];
  const float* x1 = (const float*)d_in[1];
  const float* w0 = (const float*)d_in[2];
  const float* w1 = (const float*)d_in[3];
  const float* ehy0 = (const float*)d_in[4];
  const float* ehy1 = (const float*)d_in[5];
  const float* enod0 = (const float*)d_in[6];
  const float* enod1 = (const float*)d_in[7];

  float* out = (float*)d_out;
  float* adj0 = out;                       // 640*128
  float* adj1 = out + 640 * 128;           // 384*64
  float* lossp = out + 640 * 128 + 384 * 64;

  unsigned short* nhat0 = (unsigned short*)d_ws;
  unsigned short* nhat1 = nhat0 + (size_t)BATCH * 640 * DDIM;
  int* ip = (int*)(nhat1 + (size_t)BATCH * 384 * DDIM);
  int* labels0 = ip;
  int* labels1 = labels0 + 640;
  int* cnt0 = labels1 + 384;
  int* cnt1 = cnt0 + 640;
  int* valid = cnt1 + 384;
  float* acc = (float*)(valid + 2);
  float2* sp = (float2*)((((size_t)(acc + 2)) + 255) & ~(size_t)255);
  // sp: 10 slots x 65536 gids x 8 B = 5.24 MB (ws total ~72.4 MB)

  prep_kernel<<<1024 + 16384, 256, 0, stream>>>(
      enod0, ehy0, enod1, ehy1, adj0, adj1, labels0, labels1,
      x0, w0, x1, w1, nhat0, nhat1, acc);
  cnt_kernel<<<2, 256, 0, stream>>>(labels0, cnt0, labels1, cnt1, valid);
  lse_kernel<<<4864, 128, 0, stream>>>(nhat0, labels0, nhat1, labels1, sp);
  loss_reduce<<<64, 256, 0, stream>>>(sp, cnt0, cnt1, acc);
  final_kernel<<<1, 1, 0, stream>>>(acc, valid, lossp);
}